// Round 2
// baseline (2448.051 us; speedup 1.0000x reference)
//
#include <hip/hip_runtime.h>
#include <hip/hip_bf16.h>
#include <math.h>

// LiquidNeuralNetwork: B=4096, IN=512, HS={256,128,64}, S=64, OUT=12
// Round 2: all-fp32 (reference dtypes). fp32 tiled GEMM with fused
// activation + Wo-dot epilogue; fp32 intermediates in d_ws; fp32 output.

#define BATCH 4096
#define BM 64
#define BK 16
#define SDIM 64

// One block: BM=64 batch rows x one neuron (S=64 cols), K-reduction tiled by BK.
// Epilogue: li += bi+bl; act = tanh(li)+0.1*sin(0.5li)*cos(0.3li);
//           t[b,n] = sum_s act*Wo[n,s] + bo[n]
__global__ __launch_bounds__(256) void liquid_proj_kernel(
    const float* __restrict__ x,     // [B, K]
    const float* __restrict__ Wi,    // [Nn, K, S]
    const float* __restrict__ bi,    // [Nn, S]
    const float* __restrict__ bl,    // [Nn, S]
    const float* __restrict__ Wo,    // [Nn, S]
    const float* __restrict__ bo,    // [Nn]
    float* __restrict__ t,           // [B, Nn]
    int K, int Nn)
{
    __shared__ float xs[BK][BM + 1];
    __shared__ float ws[BK][SDIM + 1];

    const int tid = threadIdx.x;
    const int tx = tid & 15;        // column group (s)
    const int ty = tid >> 4;        // row group (b)
    const int row0 = blockIdx.x * BM;
    const int n = blockIdx.y;
    const float* Wn = Wi + (size_t)n * K * SDIM;

    float acc[4][4] = {};

    for (int k0 = 0; k0 < K; k0 += BK) {
        // x tile: 64 rows x BK cols. Consecutive threads read consecutive k
        // (coalesced 16-element segments).
#pragma unroll
        for (int i = 0; i < (BM * BK) / 256; ++i) {
            int li = tid + 256 * i;
            int kk = li & (BK - 1);
            int r = li >> 4;
            xs[kk][r] = x[(size_t)(row0 + r) * K + k0 + kk];
        }
        // Wi tile: BK x 64, contiguous in memory -> coalesced.
#pragma unroll
        for (int i = 0; i < (BK * SDIM) / 256; ++i) {
            int li = tid + 256 * i;
            int s = li & 63;
            int kk = li >> 6;
            ws[kk][s] = Wn[(size_t)(k0 + kk) * SDIM + s];
        }
        __syncthreads();
#pragma unroll
        for (int kk = 0; kk < BK; ++kk) {
            float xa[4], wb[4];
#pragma unroll
            for (int i = 0; i < 4; ++i) xa[i] = xs[kk][4 * ty + i];
#pragma unroll
            for (int j = 0; j < 4; ++j) wb[j] = ws[kk][4 * tx + j];
#pragma unroll
            for (int i = 0; i < 4; ++i)
#pragma unroll
                for (int j = 0; j < 4; ++j)
                    acc[i][j] += xa[i] * wb[j];
        }
        __syncthreads();
    }

    // Fused epilogue: bias + liquid_tanh activation + dot with Wo over s.
    float part[4] = {0.f, 0.f, 0.f, 0.f};
#pragma unroll
    for (int j = 0; j < 4; ++j) {
        int c = 4 * tx + j;
        float bias = bi[n * SDIM + c] + bl[n * SDIM + c];
        float wo = Wo[n * SDIM + c];
#pragma unroll
        for (int i = 0; i < 4; ++i) {
            float v = acc[i][j] + bias;
            float act = tanhf(v) + 0.1f * sinf(0.5f * v) * cosf(0.3f * v);
            part[i] += act * wo;
        }
    }
    // Reduce across the 16 lanes sharing a row (tx dimension); stays inside
    // the 64-lane wave (ty groups of 16).
#pragma unroll
    for (int m = 1; m < 16; m <<= 1) {
#pragma unroll
        for (int i = 0; i < 4; ++i) part[i] += __shfl_xor(part[i], m, 64);
    }
    if (tx == 0) {
        float b = bo[n];
#pragma unroll
        for (int i = 0; i < 4; ++i)
            t[(size_t)(row0 + 4 * ty + i) * Nn + n] = part[i] + b;
    }
}

// h[b,n] = (t[b,n] + 0.1 * sum_m t[b,m] * L[m,n]) * a[n]
__global__ void lateral_kernel(const float* __restrict__ t,
                               const float* __restrict__ L,
                               const float* __restrict__ a,
                               float* __restrict__ h, int Nn)
{
    extern __shared__ float tb[];
    const int b = blockIdx.x;
    const int n = threadIdx.x;
    tb[n] = t[(size_t)b * Nn + n];
    __syncthreads();
    float acc = 0.f;
    for (int m = 0; m < Nn; ++m)
        acc += tb[m] * L[(size_t)m * Nn + n];
    h[(size_t)b * Nn + n] = (tb[n] + 0.1f * acc) * a[n];
}

// y[b,o] = sum_k h[b,k] * Wout[k,o] + bout[o];  K=64, OUT=12
__global__ void out_kernel(const float* __restrict__ h,
                           const float* __restrict__ Wout,
                           const float* __restrict__ bout,
                           float* __restrict__ y)
{
    int g = blockIdx.x * blockDim.x + threadIdx.x;
    if (g >= BATCH * 12) return;
    int b = g / 12;
    int o = g - 12 * b;
    float acc = bout[o];
    const float* hb = h + (size_t)b * 64;
#pragma unroll
    for (int k = 0; k < 64; ++k)
        acc += hb[k] * Wout[k * 12 + o];
    y[g] = acc;
}

extern "C" void kernel_launch(void* const* d_in, const int* in_sizes, int n_in,
                              void* d_out, int out_size, void* d_ws, size_t ws_size,
                              hipStream_t stream)
{
    (void)in_sizes; (void)n_in; (void)out_size; (void)ws_size;
    // Input order: x, {Wi,bi,bl,Wo,bo,L,a} x3, Wout, bout
    const float* x = (const float*)d_in[0];

    char* ws = (char*)d_ws;
    const size_t MB = 1024u * 1024u;
    // Workspace plan (8 MB total):
    // L0: tbuf @0 (4MB),  h0 @4MB (4MB)
    // L1: tbuf @0 (2MB),  h1 @2MB (2MB)   [input h0 @4MB]
    // L2: tbuf @4MB (1MB), h2 @5MB (1MB)  [input h1 @2MB]
    float* tbufs[3] = { (float*)ws, (float*)ws, (float*)(ws + 4 * MB) };
    float* hs[3]    = { (float*)(ws + 4 * MB), (float*)(ws + 2 * MB),
                        (float*)(ws + 5 * MB) };

    const int dims[4] = {512, 256, 128, 64};
    const float* prev = x;

    for (int l = 0; l < 3; ++l) {
        const float* Wi = (const float*)d_in[1 + 7 * l + 0];
        const float* bi = (const float*)d_in[1 + 7 * l + 1];
        const float* bl = (const float*)d_in[1 + 7 * l + 2];
        const float* Wo = (const float*)d_in[1 + 7 * l + 3];
        const float* bo = (const float*)d_in[1 + 7 * l + 4];
        const float* L  = (const float*)d_in[1 + 7 * l + 5];
        const float* a  = (const float*)d_in[1 + 7 * l + 6];
        const int K = dims[l], Nn = dims[l + 1];

        dim3 grid(BATCH / BM, Nn);
        liquid_proj_kernel<<<grid, 256, 0, stream>>>(
            prev, Wi, bi, bl, Wo, bo, tbufs[l], K, Nn);
        lateral_kernel<<<BATCH, Nn, Nn * sizeof(float), stream>>>(
            tbufs[l], L, a, hs[l], Nn);
        prev = hs[l];
    }

    const float* Wout = (const float*)d_in[22];
    const float* bout = (const float*)d_in[23];
    out_kernel<<<(BATCH * 12 + 255) / 256, 256, 0, stream>>>(
        hs[2], Wout, bout, (float*)d_out);
}

// Round 3
// 428.612 us; speedup vs baseline: 5.7116x; 5.7116x over previous
//
#include <hip/hip_runtime.h>
#include <hip/hip_bf16.h>
#include <math.h>

// LiquidNeuralNetwork: B=4096, IN=512, HS={256,128,64}, S=64, OUT=12
// Round 3: bf16 MFMA GEMM (16x16x32) with global_load_lds staging, fused
// activation+Wo epilogue. Pre-passes convert x->bf16 and Wi->bf16 [n][s][k].
// Falls back to the verified fp32 path if ws_size < 28MB.

#define BATCH 4096
#define BM 64
#define BK 32
#define BN 256   // 4 neurons per block, 1 per wave

typedef __bf16 bf16x8 __attribute__((ext_vector_type(8)));
typedef float floatx4 __attribute__((ext_vector_type(4)));

__device__ __forceinline__ void gl_lds16(const void* g, void* l) {
    __builtin_amdgcn_global_load_lds(
        (const __attribute__((address_space(1))) void*)g,
        (__attribute__((address_space(3))) void*)l, 16, 0, 0);
}

__device__ __forceinline__ float fast_tanh(float x) {
    return 1.0f - 2.0f / (__expf(2.0f * x) + 1.0f);
}
__device__ __forceinline__ float liquid_act(float v) {
    return fast_tanh(v) + 0.1f * __sinf(0.5f * v) * __cosf(0.3f * v);
}

// ---------- conversion pre-passes ----------

// x [B][K] fp32 -> xb [B][K] bf16  (n4 = total/4)
__global__ void xconv_kernel(const float* __restrict__ x,
                             __hip_bfloat16* __restrict__ xb, int n4)
{
    int g = blockIdx.x * blockDim.x + threadIdx.x;
    if (g >= n4) return;
    float4 v = ((const float4*)x)[g];
    union { ushort4 u4; __hip_bfloat16 b[4]; } o;
    o.b[0] = __float2bfloat16(v.x);
    o.b[1] = __float2bfloat16(v.y);
    o.b[2] = __float2bfloat16(v.z);
    o.b[3] = __float2bfloat16(v.w);
    ((ushort4*)xb)[g] = o.u4;
}

// Wi [Nn][K][64] fp32 -> Wt [Nn][64][K] bf16 (transpose k<->s per neuron)
__global__ __launch_bounds__(256) void wconv_kernel(
    const float* __restrict__ Wi, __hip_bfloat16* __restrict__ Wt, int K)
{
    __shared__ float lds[64][65];
    const int t = threadIdx.x;
    const int k0 = blockIdx.x * 64;
    const int n = blockIdx.y;
    const float* src = Wi + ((size_t)n * K + k0) * 64;
#pragma unroll
    for (int i = 0; i < 4; ++i) {
        int idx = t + i * 256;
        int r = idx >> 4;            // k within tile
        int s4 = (idx & 15) * 4;
        float4 v = *(const float4*)(src + (size_t)r * 64 + s4);
        lds[s4 + 0][r] = v.x;
        lds[s4 + 1][r] = v.y;
        lds[s4 + 2][r] = v.z;
        lds[s4 + 3][r] = v.w;
    }
    __syncthreads();
    __hip_bfloat16* dst = Wt + (size_t)n * 64 * K + k0;
#pragma unroll
    for (int i = 0; i < 4; ++i) {
        int idx = t + i * 256;
        int s = idx >> 4;
        int k4 = (idx & 15) * 4;
        union { ushort4 u4; __hip_bfloat16 b[4]; } o;
        o.b[0] = __float2bfloat16(lds[s][k4 + 0]);
        o.b[1] = __float2bfloat16(lds[s][k4 + 1]);
        o.b[2] = __float2bfloat16(lds[s][k4 + 2]);
        o.b[3] = __float2bfloat16(lds[s][k4 + 3]);
        *(ushort4*)(dst + (size_t)s * K + k4) = o.u4;
    }
}

// ---------- MFMA proj: t[b,n] = sum_s act(x@Wi + bi + bl) * Wo + bo ----------

__global__ __launch_bounds__(256) void liquid_proj_mfma(
    const __hip_bfloat16* __restrict__ X,   // [B][K] bf16
    const __hip_bfloat16* __restrict__ Wt,  // [Nn][64][K] bf16
    const float* __restrict__ bi, const float* __restrict__ bl,
    const float* __restrict__ Wo, const float* __restrict__ bo,
    float* __restrict__ t, int K, int Nn)
{
    __shared__ __align__(16) __hip_bfloat16 As[BM * BK];   // [64 rows][32 k]
    __shared__ __align__(16) __hip_bfloat16 Bs[BN * BK];   // [256 cols][32 k]

    const int tid = threadIdx.x;
    const int w = tid >> 6;
    const int lane = tid & 63;
    const int m = lane & 15;
    const int qd = lane >> 4;
    const int row0 = blockIdx.x * BM;
    const int n0 = blockIdx.y * 4;
    const int n = n0 + w;                 // this wave's neuron

    floatx4 acc[4][4] = {};

    const int ar = tid >> 2, aq = tid & 3;  // A staging: row, k-chunk

    for (int k0 = 0; k0 < K; k0 += BK) {
        // A: 64 rows x 32 k = 256 x 16B chunks, 1 per thread
        gl_lds16(X + (size_t)(row0 + ar) * K + k0 + aq * 8,
                 (void*)(As + tid * 8));
        // B: 256 cols x 32 k = 1024 chunks, 4 per thread
#pragma unroll
        for (int i = 0; i < 4; ++i) {
            int Li = i * 256 + tid;
            int c = Li >> 2, q = Li & 3;
            gl_lds16(Wt + ((size_t)(n0 + (c >> 6)) * 64 + (c & 63)) * K + k0 + q * 8,
                     (void*)(Bs + Li * 8));
        }
        __syncthreads();
        bf16x8 af[4], bfr[4];
#pragma unroll
        for (int rt = 0; rt < 4; ++rt)
            af[rt] = *(const bf16x8*)(As + (rt * 16 + m) * BK + qd * 8);
#pragma unroll
        for (int ct = 0; ct < 4; ++ct)
            bfr[ct] = *(const bf16x8*)(Bs + (w * 64 + ct * 16 + m) * BK + qd * 8);
#pragma unroll
        for (int rt = 0; rt < 4; ++rt)
#pragma unroll
            for (int ct = 0; ct < 4; ++ct)
                acc[rt][ct] = __builtin_amdgcn_mfma_f32_16x16x32_bf16(
                    af[rt], bfr[ct], acc[rt][ct], 0, 0, 0);
        __syncthreads();
    }

    // Epilogue: D row = rt*16 + qd*4 + reg, col s = ct*16 + m
    float bias[4], wo[4];
#pragma unroll
    for (int ct = 0; ct < 4; ++ct) {
        int s = ct * 16 + m;
        bias[ct] = bi[n * 64 + s] + bl[n * 64 + s];
        wo[ct] = Wo[n * 64 + s];
    }
    float bov = bo[n];
    float part[4][4];
#pragma unroll
    for (int rt = 0; rt < 4; ++rt)
#pragma unroll
        for (int reg = 0; reg < 4; ++reg) {
            float p = 0.f;
#pragma unroll
            for (int ct = 0; ct < 4; ++ct)
                p += liquid_act(acc[rt][ct][reg] + bias[ct]) * wo[ct];
            part[rt][reg] = p;
        }
#pragma unroll
    for (int mask = 1; mask < 16; mask <<= 1)
#pragma unroll
        for (int rt = 0; rt < 4; ++rt)
#pragma unroll
            for (int reg = 0; reg < 4; ++reg)
                part[rt][reg] += __shfl_xor(part[rt][reg], mask, 64);
    if (m == 0) {
#pragma unroll
        for (int rt = 0; rt < 4; ++rt)
#pragma unroll
            for (int reg = 0; reg < 4; ++reg)
                t[(size_t)(row0 + rt * 16 + qd * 4 + reg) * Nn + n] =
                    part[rt][reg] + bov;
    }
}

// h[b,n] = (t + 0.1 * t@L) * a  -> bf16
__global__ void lateral_bf16_kernel(const float* __restrict__ t,
                                    const float* __restrict__ L,
                                    const float* __restrict__ a,
                                    __hip_bfloat16* __restrict__ h, int Nn)
{
    extern __shared__ float tb[];
    const int b = blockIdx.x;
    const int n = threadIdx.x;
    tb[n] = t[(size_t)b * Nn + n];
    __syncthreads();
    float acc = 0.f;
    for (int mm = 0; mm < Nn; ++mm)
        acc += tb[mm] * L[(size_t)mm * Nn + n];
    h[(size_t)b * Nn + n] = __float2bfloat16((tb[n] + 0.1f * acc) * a[n]);
}

// y = h2 @ Wout + bout (h2 bf16)
__global__ void out_bf16_kernel(const __hip_bfloat16* __restrict__ h,
                                const float* __restrict__ Wout,
                                const float* __restrict__ bout,
                                float* __restrict__ y)
{
    int g = blockIdx.x * blockDim.x + threadIdx.x;
    if (g >= BATCH * 12) return;
    int b = g / 12, o = g - 12 * b;
    float acc = bout[o];
    const __hip_bfloat16* hb = h + (size_t)b * 64;
#pragma unroll
    for (int k = 0; k < 64; ++k)
        acc += __bfloat162float(hb[k]) * Wout[k * 12 + o];
    y[g] = acc;
}

// ---------- fp32 fallback path (round-2 verified) ----------

__global__ __launch_bounds__(256) void liquid_proj_f32(
    const float* __restrict__ x, const float* __restrict__ Wi,
    const float* __restrict__ bi, const float* __restrict__ bl,
    const float* __restrict__ Wo, const float* __restrict__ bo,
    float* __restrict__ t, int K, int Nn)
{
    __shared__ float xs[16][BM + 1];
    __shared__ float ws[16][64 + 1];
    const int tid = threadIdx.x;
    const int tx = tid & 15, ty = tid >> 4;
    const int row0 = blockIdx.x * BM;
    const int n = blockIdx.y;
    const float* Wn = Wi + (size_t)n * K * 64;
    float acc[4][4] = {};
    for (int k0 = 0; k0 < K; k0 += 16) {
#pragma unroll
        for (int i = 0; i < 4; ++i) {
            int li = tid + 256 * i;
            xs[li & 15][li >> 4] = x[(size_t)(row0 + (li >> 4)) * K + k0 + (li & 15)];
        }
#pragma unroll
        for (int i = 0; i < 4; ++i) {
            int li = tid + 256 * i;
            ws[li >> 6][li & 63] = Wn[(size_t)(k0 + (li >> 6)) * 64 + (li & 63)];
        }
        __syncthreads();
#pragma unroll
        for (int kk = 0; kk < 16; ++kk) {
            float xa[4], wb[4];
#pragma unroll
            for (int i = 0; i < 4; ++i) xa[i] = xs[kk][4 * ty + i];
#pragma unroll
            for (int j = 0; j < 4; ++j) wb[j] = ws[kk][4 * tx + j];
#pragma unroll
            for (int i = 0; i < 4; ++i)
#pragma unroll
                for (int j = 0; j < 4; ++j) acc[i][j] += xa[i] * wb[j];
        }
        __syncthreads();
    }
    float part[4] = {0.f, 0.f, 0.f, 0.f};
#pragma unroll
    for (int j = 0; j < 4; ++j) {
        int c = 4 * tx + j;
        float bias = bi[n * 64 + c] + bl[n * 64 + c];
        float wov = Wo[n * 64 + c];
#pragma unroll
        for (int i = 0; i < 4; ++i) {
            float v = acc[i][j] + bias;
            part[i] += (tanhf(v) + 0.1f * sinf(0.5f * v) * cosf(0.3f * v)) * wov;
        }
    }
#pragma unroll
    for (int mk = 1; mk < 16; mk <<= 1)
#pragma unroll
        for (int i = 0; i < 4; ++i) part[i] += __shfl_xor(part[i], mk, 64);
    if (tx == 0) {
        float b = bo[n];
#pragma unroll
        for (int i = 0; i < 4; ++i)
            t[(size_t)(row0 + 4 * ty + i) * Nn + n] = part[i] + b;
    }
}

__global__ void lateral_f32_kernel(const float* __restrict__ t,
                                   const float* __restrict__ L,
                                   const float* __restrict__ a,
                                   float* __restrict__ h, int Nn)
{
    extern __shared__ float tb[];
    const int b = blockIdx.x;
    const int n = threadIdx.x;
    tb[n] = t[(size_t)b * Nn + n];
    __syncthreads();
    float acc = 0.f;
    for (int mm = 0; mm < Nn; ++mm)
        acc += tb[mm] * L[(size_t)mm * Nn + n];
    h[(size_t)b * Nn + n] = (tb[n] + 0.1f * acc) * a[n];
}

__global__ void out_f32_kernel(const float* __restrict__ h,
                               const float* __restrict__ Wout,
                               const float* __restrict__ bout,
                               float* __restrict__ y)
{
    int g = blockIdx.x * blockDim.x + threadIdx.x;
    if (g >= BATCH * 12) return;
    int b = g / 12, o = g - 12 * b;
    float acc = bout[o];
    const float* hb = h + (size_t)b * 64;
#pragma unroll
    for (int k = 0; k < 64; ++k) acc += hb[k] * Wout[k * 12 + o];
    y[g] = acc;
}

extern "C" void kernel_launch(void* const* d_in, const int* in_sizes, int n_in,
                              void* d_out, int out_size, void* d_ws, size_t ws_size,
                              hipStream_t stream)
{
    (void)in_sizes; (void)n_in; (void)out_size;
    const float* x = (const float*)d_in[0];
    const float* Wout = (const float*)d_in[22];
    const float* bout = (const float*)d_in[23];
    const int dims[4] = {512, 256, 128, 64};
    char* ws = (char*)d_ws;
    const size_t MB = 1024u * 1024u;

    if (ws_size >= 28 * MB) {
        // fast path: Wt@0 (16MB), xb@16MB (4MB), t@20MB (4MB), h0@24MB, h1@26MB, h2@27MB
        __hip_bfloat16* Wt = (__hip_bfloat16*)ws;
        __hip_bfloat16* xb = (__hip_bfloat16*)(ws + 16 * MB);
        float* tbuf = (float*)(ws + 20 * MB);
        __hip_bfloat16* hb[3] = {(__hip_bfloat16*)(ws + 24 * MB),
                                 (__hip_bfloat16*)(ws + 26 * MB),
                                 (__hip_bfloat16*)(ws + 27 * MB)};

        xconv_kernel<<<(BATCH * 512 / 4 + 255) / 256, 256, 0, stream>>>(x, xb, BATCH * 512 / 4);
        const __hip_bfloat16* prev = xb;
        for (int l = 0; l < 3; ++l) {
            const float* Wi = (const float*)d_in[1 + 7 * l + 0];
            const float* bi = (const float*)d_in[1 + 7 * l + 1];
            const float* bl = (const float*)d_in[1 + 7 * l + 2];
            const float* Wo = (const float*)d_in[1 + 7 * l + 3];
            const float* bo = (const float*)d_in[1 + 7 * l + 4];
            const float* L  = (const float*)d_in[1 + 7 * l + 5];
            const float* a  = (const float*)d_in[1 + 7 * l + 6];
            const int K = dims[l], Nn = dims[l + 1];

            wconv_kernel<<<dim3(K / 64, Nn), 256, 0, stream>>>(Wi, Wt, K);
            liquid_proj_mfma<<<dim3(BATCH / BM, Nn / 4), 256, 0, stream>>>(
                prev, Wt, bi, bl, Wo, bo, tbuf, K, Nn);
            lateral_bf16_kernel<<<BATCH, Nn, Nn * sizeof(float), stream>>>(
                tbuf, L, a, hb[l], Nn);
            prev = hb[l];
        }
        out_bf16_kernel<<<(BATCH * 12 + 255) / 256, 256, 0, stream>>>(
            hb[2], Wout, bout, (float*)d_out);
    } else {
        // fallback: round-2 fp32 path (8MB ws)
        float* tbufs[3] = {(float*)ws, (float*)ws, (float*)(ws + 4 * MB)};
        float* hs[3] = {(float*)(ws + 4 * MB), (float*)(ws + 2 * MB),
                        (float*)(ws + 5 * MB)};
        const float* prev = x;
        for (int l = 0; l < 3; ++l) {
            const float* Wi = (const float*)d_in[1 + 7 * l + 0];
            const float* bi = (const float*)d_in[1 + 7 * l + 1];
            const float* bl = (const float*)d_in[1 + 7 * l + 2];
            const float* Wo = (const float*)d_in[1 + 7 * l + 3];
            const float* bo = (const float*)d_in[1 + 7 * l + 4];
            const float* L  = (const float*)d_in[1 + 7 * l + 5];
            const float* a  = (const float*)d_in[1 + 7 * l + 6];
            const int K = dims[l], Nn = dims[l + 1];
            liquid_proj_f32<<<dim3(BATCH / BM, Nn), 256, 0, stream>>>(
                prev, Wi, bi, bl, Wo, bo, tbufs[l], K, Nn);
            lateral_f32_kernel<<<BATCH, Nn, Nn * sizeof(float), stream>>>(
                tbufs[l], L, a, hs[l], Nn);
            prev = hs[l];
        }
        out_f32_kernel<<<(BATCH * 12 + 255) / 256, 256, 0, stream>>>(
            hs[2], Wout, bout, (float*)d_out);
    }
}

// Round 5
// 414.377 us; speedup vs baseline: 5.9078x; 1.0344x over previous
//
#include <hip/hip_runtime.h>
#include <hip/hip_bf16.h>
#include <math.h>

// LiquidNeuralNetwork: B=4096, IN=512, HS={256,128,64}, S=64, OUT=12
// Round 5: round-4 structure with the wconv layer-2 bug fixed (K=128, 2
// k-tiles, 1MB Wt2) and workspace re-laid to avoid the Wt2/xb overlap.

#define BATCH 4096
#define BM 128
#define BKK 64

typedef __bf16 bf16x8 __attribute__((ext_vector_type(8)));
typedef float floatx4 __attribute__((ext_vector_type(4)));

__device__ __forceinline__ void gl_lds16(const void* g, void* l) {
    __builtin_amdgcn_global_load_lds(
        (const __attribute__((address_space(1))) void*)g,
        (__attribute__((address_space(3))) void*)l, 16, 0, 0);
}

__device__ __forceinline__ float liquid_act(float v) {
    // tanh(v) + 0.1*sin(0.5v)*cos(0.3v) ; sin*cos -> 0.05*(sin(0.8v)+sin(0.2v))
    float e = __expf(2.0f * v);
    float th = 1.0f - __fdividef(2.0f, e + 1.0f);
    return th + 0.05f * (__sinf(0.8f * v) + __sinf(0.2f * v));
}

// ---------- conversion pre-passes ----------

__global__ void xconv_kernel(const float* __restrict__ x,
                             __hip_bfloat16* __restrict__ xb, int n4)
{
    int g = blockIdx.x * blockDim.x + threadIdx.x;
    if (g >= n4) return;
    float4 v = ((const float4*)x)[g];
    union { ushort4 u4; __hip_bfloat16 b[4]; } o;
    o.b[0] = __float2bfloat16(v.x);
    o.b[1] = __float2bfloat16(v.y);
    o.b[2] = __float2bfloat16(v.z);
    o.b[3] = __float2bfloat16(v.w);
    ((ushort4*)xb)[g] = o.u4;
}

// Wi [Nn][K][64] fp32 -> Wt [Nn][64][K] bf16 (one 64-k tile per block)
__device__ __forceinline__ void wconv_tile(const float* __restrict__ Wi,
                                           __hip_bfloat16* __restrict__ Wt,
                                           int K, int n, int k0, int t)
{
    __shared__ float lds[64][65];
    const float* src = Wi + ((size_t)n * K + k0) * 64;
#pragma unroll
    for (int i = 0; i < 4; ++i) {
        int idx = t + i * 256;
        int r = idx >> 4;            // k within tile
        int s4 = (idx & 15) * 4;
        float4 v = *(const float4*)(src + (size_t)r * 64 + s4);
        lds[s4 + 0][r] = v.x;
        lds[s4 + 1][r] = v.y;
        lds[s4 + 2][r] = v.z;
        lds[s4 + 3][r] = v.w;
    }
    __syncthreads();
    __hip_bfloat16* dst = Wt + (size_t)n * 64 * K + k0;
#pragma unroll
    for (int i = 0; i < 4; ++i) {
        int idx = t + i * 256;
        int s = idx >> 4;
        int k4 = (idx & 15) * 4;
        union { ushort4 u4; __hip_bfloat16 b[4]; } o;
        o.b[0] = __float2bfloat16(lds[s][k4 + 0]);
        o.b[1] = __float2bfloat16(lds[s][k4 + 1]);
        o.b[2] = __float2bfloat16(lds[s][k4 + 2]);
        o.b[3] = __float2bfloat16(lds[s][k4 + 3]);
        *(ushort4*)(dst + (size_t)s * K + k4) = o.u4;
    }
}

// L0: 256 n x 8 ktiles (K=512) = 2048 blocks
// L1: 128 n x 4 ktiles (K=256) = 512 blocks
// L2:  64 n x 2 ktiles (K=128) = 128 blocks   [round-4 bug: had 1 ktile, K=64]
__global__ __launch_bounds__(256) void wconv_all(
    const float* __restrict__ Wi0, const float* __restrict__ Wi1,
    const float* __restrict__ Wi2,
    __hip_bfloat16* __restrict__ Wt0, __hip_bfloat16* __restrict__ Wt1,
    __hip_bfloat16* __restrict__ Wt2)
{
    int bid = blockIdx.x;
    int t = threadIdx.x;
    if (bid < 2048) {
        wconv_tile(Wi0, Wt0, 512, bid >> 3, (bid & 7) * 64, t);
    } else if (bid < 2560) {
        int r = bid - 2048;
        wconv_tile(Wi1, Wt1, 256, r >> 2, (r & 3) * 64, t);
    } else {
        int r = bid - 2560;          // [0,128)
        wconv_tile(Wi2, Wt2, 128, r >> 1, (r & 1) * 64, t);
    }
}

// ---------- MFMA proj: t[b,n] = sum_s act(x@Wi + bi + bl)*Wo + bo ----------
// Block: 128 rows x 2 neurons (128 s-cols). 256 threads = 4 waves (2M x 2N).

__global__ __launch_bounds__(256) void liquid_proj_mfma(
    const __hip_bfloat16* __restrict__ X,   // [B][K] bf16
    const __hip_bfloat16* __restrict__ Wt,  // [Nn][64][K] bf16
    const float* __restrict__ bi, const float* __restrict__ bl,
    const float* __restrict__ Wo, const float* __restrict__ bo,
    __hip_bfloat16* __restrict__ t, int K, int Nn)
{
    __shared__ __align__(16) __hip_bfloat16 As[BM * BKK];   // 16 KB
    __shared__ __align__(16) __hip_bfloat16 Bs[128 * BKK];  // 16 KB

    const int tid = threadIdx.x;
    const int wm = (tid >> 6) & 1;        // M half
    const int wn = tid >> 7;              // neuron within block
    const int lane = tid & 63;
    const int m = lane & 15;
    const int qd = lane >> 4;
    const int row0 = blockIdx.x * BM;
    const int n0 = blockIdx.y * 2;
    const int n = n0 + wn;

    floatx4 acc[4][4] = {};

    for (int k0 = 0; k0 < K; k0 += BKK) {
        // A: 128 rows x 64 k = 1024 x 16B chunks, 4/thread
#pragma unroll
        for (int i = 0; i < 4; ++i) {
            int Li = i * 256 + tid;
            int r = Li >> 3, q = Li & 7;
            gl_lds16(X + (size_t)(row0 + r) * K + k0 + q * 8,
                     (void*)(As + Li * 8));
        }
        // B: 128 cols x 64 k
#pragma unroll
        for (int i = 0; i < 4; ++i) {
            int Li = i * 256 + tid;
            int c = Li >> 3, q = Li & 7;
            gl_lds16(Wt + ((size_t)(n0 + (c >> 6)) * 64 + (c & 63)) * K + k0 + q * 8,
                     (void*)(Bs + Li * 8));
        }
        __syncthreads();
        bf16x8 af[4][2], bfr[4][2];
#pragma unroll
        for (int rt = 0; rt < 4; ++rt)
#pragma unroll
            for (int kk = 0; kk < 2; ++kk)
                af[rt][kk] = *(const bf16x8*)(As + (wm * 64 + rt * 16 + m) * BKK + kk * 32 + qd * 8);
#pragma unroll
        for (int ct = 0; ct < 4; ++ct)
#pragma unroll
            for (int kk = 0; kk < 2; ++kk)
                bfr[ct][kk] = *(const bf16x8*)(Bs + (wn * 64 + ct * 16 + m) * BKK + kk * 32 + qd * 8);
#pragma unroll
        for (int kk = 0; kk < 2; ++kk)
#pragma unroll
            for (int rt = 0; rt < 4; ++rt)
#pragma unroll
                for (int ct = 0; ct < 4; ++ct)
                    acc[rt][ct] = __builtin_amdgcn_mfma_f32_16x16x32_bf16(
                        af[rt][kk], bfr[ct][kk], acc[rt][ct], 0, 0, 0);
        __syncthreads();
    }

    // Epilogue: D row = wm*64 + rt*16 + qd*4 + reg, col s = ct*16 + m.
    float bias[4], wo[4];
#pragma unroll
    for (int ct = 0; ct < 4; ++ct) {
        int s = ct * 16 + m;
        bias[ct] = bi[n * 64 + s] + bl[n * 64 + s];
        wo[ct] = Wo[n * 64 + s];
    }
    float bov = bo[n];
    float part[4][4];
#pragma unroll
    for (int rt = 0; rt < 4; ++rt)
#pragma unroll
        for (int reg = 0; reg < 4; ++reg) {
            float p = 0.f;
#pragma unroll
            for (int ct = 0; ct < 4; ++ct)
                p += liquid_act(acc[rt][ct][reg] + bias[ct]) * wo[ct];
            part[rt][reg] = p;
        }
#pragma unroll
    for (int mask = 1; mask < 16; mask <<= 1)
#pragma unroll
        for (int rt = 0; rt < 4; ++rt)
#pragma unroll
            for (int reg = 0; reg < 4; ++reg)
                part[rt][reg] += __shfl_xor(part[rt][reg], mask, 64);
    if (m == 0) {
#pragma unroll
        for (int rt = 0; rt < 4; ++rt)
#pragma unroll
            for (int reg = 0; reg < 4; ++reg)
                t[(size_t)(row0 + wm * 64 + rt * 16 + qd * 4 + reg) * Nn + n] =
                    __float2bfloat16(part[rt][reg] + bov);
    }
}

// ---------- lateral (+ fused output head on final layer) ----------

template <int NN, int NNSH, bool FINAL>
__global__ __launch_bounds__(256) void lateral_fused(
    const __hip_bfloat16* __restrict__ t,   // [B][NN] bf16
    const float* __restrict__ Lm,           // [NN][NN]
    const float* __restrict__ a,            // [NN]
    __hip_bfloat16* __restrict__ h,         // [B][NN] bf16 (unused if FINAL)
    const float* __restrict__ Wout,         // [64][12] (FINAL only)
    const float* __restrict__ bout,         // [12]
    float* __restrict__ y)                  // [B][12]
{
    constexpr int RPT = NN / 16;            // rows per thread
    __shared__ float tbT[NN][20];           // [col][row], padded
    __shared__ float hb[16][65];            // FINAL h tile

    const int tid = threadIdx.x;
    const int row0 = blockIdx.x * 16;

#pragma unroll
    for (int i = 0; i < NN / 16; ++i) {
        int idx = tid + i * 256;
        int r = idx >> NNSH;
        int c = idx & (NN - 1);
        tbT[c][r] = __bfloat162float(t[(size_t)(row0 + r) * NN + c]);
    }
    __syncthreads();

    const int c = tid & (NN - 1);
    const int rb = (tid >> NNSH) * RPT;
    float acc[RPT];
#pragma unroll
    for (int r = 0; r < RPT; ++r) acc[r] = 0.f;

    for (int mm = 0; mm < NN; ++mm) {
        float lv = Lm[mm * NN + c];
#pragma unroll
        for (int rr = 0; rr < RPT / 4; ++rr) {
            float4 tv = *(const float4*)&tbT[mm][rb + 4 * rr];
            acc[4 * rr + 0] += tv.x * lv;
            acc[4 * rr + 1] += tv.y * lv;
            acc[4 * rr + 2] += tv.z * lv;
            acc[4 * rr + 3] += tv.w * lv;
        }
    }
    float av = a[c];
#pragma unroll
    for (int r = 0; r < RPT; ++r) {
        float hv = (tbT[c][rb + r] + 0.1f * acc[r]) * av;
        if constexpr (FINAL) {
            hb[rb + r][c] = hv;
        } else {
            h[(size_t)(row0 + rb + r) * NN + c] = __float2bfloat16(hv);
        }
    }
    if constexpr (FINAL) {
        __syncthreads();
        if (tid < 192) {
            int r = tid / 12, o = tid - 12 * r;
            float accy = bout[o];
#pragma unroll
            for (int k = 0; k < 64; ++k)
                accy += hb[r][k] * Wout[k * 12 + o];
            y[(size_t)(row0 + r) * 12 + o] = accy;
        }
    }
}

// ---------- fp32 fallback path (round-2 verified) ----------

__global__ __launch_bounds__(256) void liquid_proj_f32(
    const float* __restrict__ x, const float* __restrict__ Wi,
    const float* __restrict__ bi, const float* __restrict__ bl,
    const float* __restrict__ Wo, const float* __restrict__ bo,
    float* __restrict__ t, int K, int Nn)
{
    __shared__ float xs[16][65];
    __shared__ float ws[16][65];
    const int tid = threadIdx.x;
    const int tx = tid & 15, ty = tid >> 4;
    const int row0 = blockIdx.x * 64;
    const int n = blockIdx.y;
    const float* Wn = Wi + (size_t)n * K * 64;
    float acc[4][4] = {};
    for (int k0 = 0; k0 < K; k0 += 16) {
#pragma unroll
        for (int i = 0; i < 4; ++i) {
            int li = tid + 256 * i;
            xs[li & 15][li >> 4] = x[(size_t)(row0 + (li >> 4)) * K + k0 + (li & 15)];
        }
#pragma unroll
        for (int i = 0; i < 4; ++i) {
            int li = tid + 256 * i;
            ws[li >> 6][li & 63] = Wn[(size_t)(k0 + (li >> 6)) * 64 + (li & 63)];
        }
        __syncthreads();
#pragma unroll
        for (int kk = 0; kk < 16; ++kk) {
            float xa[4], wb[4];
#pragma unroll
            for (int i = 0; i < 4; ++i) xa[i] = xs[kk][4 * ty + i];
#pragma unroll
            for (int j = 0; j < 4; ++j) wb[j] = ws[kk][4 * tx + j];
#pragma unroll
            for (int i = 0; i < 4; ++i)
#pragma unroll
                for (int j = 0; j < 4; ++j) acc[i][j] += xa[i] * wb[j];
        }
        __syncthreads();
    }
    float part[4] = {0.f, 0.f, 0.f, 0.f};
#pragma unroll
    for (int j = 0; j < 4; ++j) {
        int cc = 4 * tx + j;
        float bias = bi[n * 64 + cc] + bl[n * 64 + cc];
        float wov = Wo[n * 64 + cc];
#pragma unroll
        for (int i = 0; i < 4; ++i) {
            float v = acc[i][j] + bias;
            part[i] += (tanhf(v) + 0.1f * sinf(0.5f * v) * cosf(0.3f * v)) * wov;
        }
    }
#pragma unroll
    for (int mk = 1; mk < 16; mk <<= 1)
#pragma unroll
        for (int i = 0; i < 4; ++i) part[i] += __shfl_xor(part[i], mk, 64);
    if (tx == 0) {
        float b = bo[n];
#pragma unroll
        for (int i = 0; i < 4; ++i)
            t[(size_t)(row0 + 4 * ty + i) * Nn + n] = part[i] + b;
    }
}

__global__ void lateral_f32_kernel(const float* __restrict__ t,
                                   const float* __restrict__ L,
                                   const float* __restrict__ a,
                                   float* __restrict__ h, int Nn)
{
    extern __shared__ float tb[];
    const int b = blockIdx.x;
    const int n = threadIdx.x;
    tb[n] = t[(size_t)b * Nn + n];
    __syncthreads();
    float acc = 0.f;
    for (int mm = 0; mm < Nn; ++mm)
        acc += tb[mm] * L[(size_t)mm * Nn + n];
    h[(size_t)b * Nn + n] = (tb[n] + 0.1f * acc) * a[n];
}

__global__ void out_f32_kernel(const float* __restrict__ h,
                               const float* __restrict__ Wout,
                               const float* __restrict__ bout,
                               float* __restrict__ y)
{
    int g = blockIdx.x * blockDim.x + threadIdx.x;
    if (g >= BATCH * 12) return;
    int b = g / 12, o = g - 12 * b;
    float acc = bout[o];
    const float* hb = h + (size_t)b * 64;
#pragma unroll
    for (int k = 0; k < 64; ++k) acc += hb[k] * Wout[k * 12 + o];
    y[g] = acc;
}

extern "C" void kernel_launch(void* const* d_in, const int* in_sizes, int n_in,
                              void* d_out, int out_size, void* d_ws, size_t ws_size,
                              hipStream_t stream)
{
    (void)in_sizes; (void)n_in; (void)out_size;
    const float* x = (const float*)d_in[0];
    const float* Wout = (const float*)d_in[22];
    const float* bout = (const float*)d_in[23];
    const int dims[4] = {512, 256, 128, 64};
    char* ws = (char*)d_ws;
    const size_t MB = 1024u * 1024u;

    if (ws_size >= 27 * MB) {
        // Layout (27 MB, all disjoint except deliberate xb/h0/h1 staging):
        // Wt0 [0,16) Wt1 [16,20) Wt2 [20,21)
        // xb  [21,25)  (h0 [21,23) and h1 [23,24) reuse it after xb is dead)
        // tbuf [25,27)
        __hip_bfloat16* Wt0 = (__hip_bfloat16*)ws;
        __hip_bfloat16* Wt1 = (__hip_bfloat16*)(ws + 16 * MB);
        __hip_bfloat16* Wt2 = (__hip_bfloat16*)(ws + 20 * MB);
        __hip_bfloat16* Wts[3] = {Wt0, Wt1, Wt2};
        __hip_bfloat16* xb = (__hip_bfloat16*)(ws + 21 * MB);
        __hip_bfloat16* h0 = xb;                               // [21,23)
        __hip_bfloat16* h1 = (__hip_bfloat16*)(ws + 23 * MB);  // [23,24)
        __hip_bfloat16* tbuf = (__hip_bfloat16*)(ws + 25 * MB);

        xconv_kernel<<<2048, 256, 0, stream>>>(x, xb, BATCH * 512 / 4);
        wconv_all<<<2688, 256, 0, stream>>>(
            (const float*)d_in[1], (const float*)d_in[8], (const float*)d_in[15],
            Wt0, Wt1, Wt2);

        const __hip_bfloat16* prev = xb;
        const __hip_bfloat16* hbuf[3] = {h0, h1, nullptr};
        for (int l = 0; l < 3; ++l) {
            const float* bi = (const float*)d_in[1 + 7 * l + 1];
            const float* bl = (const float*)d_in[1 + 7 * l + 2];
            const float* Wo = (const float*)d_in[1 + 7 * l + 3];
            const float* bo = (const float*)d_in[1 + 7 * l + 4];
            const float* L  = (const float*)d_in[1 + 7 * l + 5];
            const float* a  = (const float*)d_in[1 + 7 * l + 6];
            const int K = dims[l], Nn = dims[l + 1];

            liquid_proj_mfma<<<dim3(BATCH / BM, Nn / 2), 256, 0, stream>>>(
                prev, Wts[l], bi, bl, Wo, bo, tbuf, K, Nn);
            if (l == 0)
                lateral_fused<256, 8, false><<<BATCH / 16, 256, 0, stream>>>(
                    tbuf, L, a, h0, nullptr, nullptr, nullptr);
            else if (l == 1)
                lateral_fused<128, 7, false><<<BATCH / 16, 256, 0, stream>>>(
                    tbuf, L, a, h1, nullptr, nullptr, nullptr);
            else
                lateral_fused<64, 6, true><<<BATCH / 16, 256, 0, stream>>>(
                    tbuf, L, a, nullptr, Wout, bout, (float*)d_out);
            prev = hbuf[l];
        }
    } else {
        // fallback: round-2 fp32 path (8MB ws)
        float* tbufs[3] = {(float*)ws, (float*)ws, (float*)(ws + 4 * MB)};
        float* hs[3] = {(float*)(ws + 4 * MB), (float*)(ws + 2 * MB),
                        (float*)(ws + 5 * MB)};
        const float* prev = x;
        for (int l = 0; l < 3; ++l) {
            const float* Wi = (const float*)d_in[1 + 7 * l + 0];
            const float* bi = (const float*)d_in[1 + 7 * l + 1];
            const float* bl = (const float*)d_in[1 + 7 * l + 2];
            const float* Wo = (const float*)d_in[1 + 7 * l + 3];
            const float* bo = (const float*)d_in[1 + 7 * l + 4];
            const float* L  = (const float*)d_in[1 + 7 * l + 5];
            const float* a  = (const float*)d_in[1 + 7 * l + 6];
            const int K = dims[l], Nn = dims[l + 1];
            liquid_proj_f32<<<dim3(BATCH / 64, Nn), 256, 0, stream>>>(
                prev, Wi, bi, bl, Wo, bo, tbufs[l], K, Nn);
            lateral_f32_kernel<<<BATCH, Nn, Nn * sizeof(float), stream>>>(
                tbufs[l], L, a, hs[l], Nn);
            prev = hs[l];
        }
        out_f32_kernel<<<(BATCH * 12 + 255) / 256, 256, 0, stream>>>(
            hs[2], Wout, bout, (float*)d_out);
    }
}

// Round 6
// 395.733 us; speedup vs baseline: 6.1861x; 1.0471x over previous
//
#include <hip/hip_runtime.h>
#include <hip/hip_bf16.h>
#include <math.h>

// LiquidNeuralNetwork: B=4096, IN=512, HS={256,128,64}, S=64, OUT=12
// Round 6: epilogue-bound fix — 32x64 wave tiles (32 AGPR acc), 512-thread
// blocks, bias folded into acc init, XCD swizzle, merged convert pass.

#define BATCH 4096

typedef __bf16 bf16x8 __attribute__((ext_vector_type(8)));
typedef float floatx4 __attribute__((ext_vector_type(4)));

__device__ __forceinline__ void gl_lds16(const void* g, void* l) {
    __builtin_amdgcn_global_load_lds(
        (const __attribute__((address_space(1))) void*)g,
        (__attribute__((address_space(3))) void*)l, 16, 0, 0);
}

__device__ __forceinline__ float liquid_act(float v) {
    // tanh(v) + 0.1*sin(0.5v)*cos(0.3v) = tanh(v) + 0.05*(sin(0.8v)+sin(0.2v))
    float e = __expf(2.0f * v);
    float th = 1.0f - __fdividef(2.0f, e + 1.0f);
    return th + 0.05f * (__sinf(0.8f * v) + __sinf(0.2f * v));
}

// ---------- merged conversion pre-pass ----------

__device__ __forceinline__ void wconv_tile(const float* __restrict__ Wi,
                                           __hip_bfloat16* __restrict__ Wt,
                                           int K, int n, int k0, int t)
{
    __shared__ float lds[64][65];
    const float* src = Wi + ((size_t)n * K + k0) * 64;
#pragma unroll
    for (int i = 0; i < 4; ++i) {
        int idx = t + i * 256;
        int r = idx >> 4;
        int s4 = (idx & 15) * 4;
        float4 v = *(const float4*)(src + (size_t)r * 64 + s4);
        lds[s4 + 0][r] = v.x;
        lds[s4 + 1][r] = v.y;
        lds[s4 + 2][r] = v.z;
        lds[s4 + 3][r] = v.w;
    }
    __syncthreads();
    __hip_bfloat16* dst = Wt + (size_t)n * 64 * K + k0;
#pragma unroll
    for (int i = 0; i < 4; ++i) {
        int idx = t + i * 256;
        int s = idx >> 4;
        int k4 = (idx & 15) * 4;
        union { ushort4 u4; __hip_bfloat16 b[4]; } o;
        o.b[0] = __float2bfloat16(lds[s][k4 + 0]);
        o.b[1] = __float2bfloat16(lds[s][k4 + 1]);
        o.b[2] = __float2bfloat16(lds[s][k4 + 2]);
        o.b[3] = __float2bfloat16(lds[s][k4 + 3]);
        *(ushort4*)(dst + (size_t)s * K + k4) = o.u4;
    }
}

// blocks [0,2048): xconv; [2048,4096): Wi0; [4096,4608): Wi1; [4608,4736): Wi2
__global__ __launch_bounds__(256) void conv_all(
    const float* __restrict__ x, __hip_bfloat16* __restrict__ xb,
    const float* __restrict__ Wi0, const float* __restrict__ Wi1,
    const float* __restrict__ Wi2,
    __hip_bfloat16* __restrict__ Wt0, __hip_bfloat16* __restrict__ Wt1,
    __hip_bfloat16* __restrict__ Wt2)
{
    int bid = blockIdx.x;
    int t = threadIdx.x;
    if (bid < 2048) {
        int g = bid * 256 + t;                 // < 4096*512/4
        float4 v = ((const float4*)x)[g];
        union { ushort4 u4; __hip_bfloat16 b[4]; } o;
        o.b[0] = __float2bfloat16(v.x);
        o.b[1] = __float2bfloat16(v.y);
        o.b[2] = __float2bfloat16(v.z);
        o.b[3] = __float2bfloat16(v.w);
        ((ushort4*)xb)[g] = o.u4;
    } else if (bid < 4096) {
        int r = bid - 2048;
        wconv_tile(Wi0, Wt0, 512, r >> 3, (r & 7) * 64, t);
    } else if (bid < 4608) {
        int r = bid - 4096;
        wconv_tile(Wi1, Wt1, 256, r >> 2, (r & 3) * 64, t);
    } else {
        int r = bid - 4608;
        wconv_tile(Wi2, Wt2, 128, r >> 1, (r & 1) * 64, t);
    }
}

// ---------- MFMA proj: t[b,n] = sum_s act(x@Wi + bi + bl)*Wo + bo ----------
// Block: 512 threads = 8 waves (2 row-halves x 4 neurons); 64 rows x 4 neurons.
// Wave tile: 32 rows x 64 s -> acc[2][4] = 32 AGPRs. BK=64.
// Grid: 1D, XCD-swizzled: same-XCD blocks iterate row-groups for one n-group.

__global__ __launch_bounds__(512, 4) void liquid_proj_mfma(
    const __hip_bfloat16* __restrict__ X,   // [B][K] bf16
    const __hip_bfloat16* __restrict__ Wt,  // [Nn][64][K] bf16
    const float* __restrict__ bi, const float* __restrict__ bl,
    const float* __restrict__ Wo, const float* __restrict__ bo,
    __hip_bfloat16* __restrict__ t, int K, int Nn)
{
    __shared__ __align__(16) __hip_bfloat16 As[64 * 64];    // 8 KB
    __shared__ __align__(16) __hip_bfloat16 Bs[256 * 64];   // 32 KB

    const int tid = threadIdx.x;
    const int wid = tid >> 6;
    const int wm = wid & 1;               // row half (32 rows each)
    const int wn = wid >> 1;              // neuron within block [0,4)
    const int lane = tid & 63;
    const int m = lane & 15;
    const int qd = lane >> 4;

    // swizzle: bid = (n_grp*8 + row_local)*8 + xcd ; row_grp = row_local*8+xcd
    const int bid = blockIdx.x;
    const int xcd = bid & 7;
    const int s = bid >> 3;
    const int n_grp = s >> 3;
    const int row_grp = ((s & 7) << 3) | xcd;
    const int row0 = row_grp * 64;
    const int n0 = n_grp * 4;
    const int n = n0 + wn;

    // bias folded into accumulator init: acc starts at bi+bl for col s=ct*16+m
    floatx4 acc[2][4];
#pragma unroll
    for (int ct = 0; ct < 4; ++ct) {
        int sc = ct * 16 + m;
        float bv = bi[n * 64 + sc] + bl[n * 64 + sc];
        floatx4 b4 = {bv, bv, bv, bv};
        acc[0][ct] = b4;
        acc[1][ct] = b4;
    }

    for (int k0 = 0; k0 < K; k0 += 64) {
        // A: 64 rows x 64 k = 512 x 16B chunks, 1/thread
        {
            int r = tid >> 3, q = tid & 7;
            gl_lds16(X + (size_t)(row0 + r) * K + k0 + q * 8,
                     (void*)(As + tid * 8));
        }
        // B: 256 cols x 64 k = 2048 chunks, 4/thread
#pragma unroll
        for (int i = 0; i < 4; ++i) {
            int Li = i * 512 + tid;
            int c = Li >> 3, q = Li & 7;
            gl_lds16(Wt + ((size_t)(n0 + (c >> 6)) * 64 + (c & 63)) * K + k0 + q * 8,
                     (void*)(Bs + Li * 8));
        }
        __syncthreads();
#pragma unroll
        for (int kk = 0; kk < 2; ++kk) {
            bf16x8 af[2], bfr[4];
#pragma unroll
            for (int rt = 0; rt < 2; ++rt)
                af[rt] = *(const bf16x8*)(As + (wm * 32 + rt * 16 + m) * 64 + kk * 32 + qd * 8);
#pragma unroll
            for (int ct = 0; ct < 4; ++ct)
                bfr[ct] = *(const bf16x8*)(Bs + (wn * 64 + ct * 16 + m) * 64 + kk * 32 + qd * 8);
#pragma unroll
            for (int rt = 0; rt < 2; ++rt)
#pragma unroll
                for (int ct = 0; ct < 4; ++ct)
                    acc[rt][ct] = __builtin_amdgcn_mfma_f32_16x16x32_bf16(
                        af[rt], bfr[ct], acc[rt][ct], 0, 0, 0);
        }
        __syncthreads();
    }

    // Epilogue: D row = row0 + wm*32 + rt*16 + qd*4 + reg, col s = ct*16+m.
    float wo[4];
#pragma unroll
    for (int ct = 0; ct < 4; ++ct)
        wo[ct] = Wo[n * 64 + ct * 16 + m];
    float bov = bo[n];
    float part[2][4];
#pragma unroll
    for (int rt = 0; rt < 2; ++rt)
#pragma unroll
        for (int reg = 0; reg < 4; ++reg) {
            float p = 0.f;
#pragma unroll
            for (int ct = 0; ct < 4; ++ct)
                p += liquid_act(acc[rt][ct][reg]) * wo[ct];
            part[rt][reg] = p;
        }
#pragma unroll
    for (int mask = 1; mask < 16; mask <<= 1)
#pragma unroll
        for (int rt = 0; rt < 2; ++rt)
#pragma unroll
            for (int reg = 0; reg < 4; ++reg)
                part[rt][reg] += __shfl_xor(part[rt][reg], mask, 64);
    if (m == 0) {
#pragma unroll
        for (int rt = 0; rt < 2; ++rt)
#pragma unroll
            for (int reg = 0; reg < 4; ++reg)
                t[(size_t)(row0 + wm * 32 + rt * 16 + qd * 4 + reg) * Nn + n] =
                    __float2bfloat16(part[rt][reg] + bov);
    }
}

// ---------- lateral (+ fused output head on final layer) ----------

template <int NN, int NNSH, bool FINAL>
__global__ __launch_bounds__(256) void lateral_fused(
    const __hip_bfloat16* __restrict__ t,   // [B][NN] bf16
    const float* __restrict__ Lm,           // [NN][NN]
    const float* __restrict__ a,            // [NN]
    __hip_bfloat16* __restrict__ h,         // [B][NN] bf16 (unused if FINAL)
    const float* __restrict__ Wout,         // [64][12] (FINAL only)
    const float* __restrict__ bout,         // [12]
    float* __restrict__ y)                  // [B][12]
{
    constexpr int RPT = NN / 16;
    __shared__ float tbT[NN][20];
    __shared__ float hb[16][65];

    const int tid = threadIdx.x;
    const int row0 = blockIdx.x * 16;

#pragma unroll
    for (int i = 0; i < NN / 16; ++i) {
        int idx = tid + i * 256;
        int r = idx >> NNSH;
        int c = idx & (NN - 1);
        tbT[c][r] = __bfloat162float(t[(size_t)(row0 + r) * NN + c]);
    }
    __syncthreads();

    const int c = tid & (NN - 1);
    const int rb = (tid >> NNSH) * RPT;
    float acc[RPT];
#pragma unroll
    for (int r = 0; r < RPT; ++r) acc[r] = 0.f;

    for (int mm = 0; mm < NN; ++mm) {
        float lv = Lm[mm * NN + c];
#pragma unroll
        for (int rr = 0; rr < RPT / 4; ++rr) {
            float4 tv = *(const float4*)&tbT[mm][rb + 4 * rr];
            acc[4 * rr + 0] += tv.x * lv;
            acc[4 * rr + 1] += tv.y * lv;
            acc[4 * rr + 2] += tv.z * lv;
            acc[4 * rr + 3] += tv.w * lv;
        }
    }
    float av = a[c];
#pragma unroll
    for (int r = 0; r < RPT; ++r) {
        float hv = (tbT[c][rb + r] + 0.1f * acc[r]) * av;
        if constexpr (FINAL) {
            hb[rb + r][c] = hv;
        } else {
            h[(size_t)(row0 + rb + r) * NN + c] = __float2bfloat16(hv);
        }
    }
    if constexpr (FINAL) {
        __syncthreads();
        if (tid < 192) {
            int r = tid / 12, o = tid - 12 * r;
            float accy = bout[o];
#pragma unroll
            for (int k = 0; k < 64; ++k)
                accy += hb[r][k] * Wout[k * 12 + o];
            y[(size_t)(row0 + r) * 12 + o] = accy;
        }
    }
}

// ---------- fp32 fallback path (round-2 verified) ----------

__global__ __launch_bounds__(256) void liquid_proj_f32(
    const float* __restrict__ x, const float* __restrict__ Wi,
    const float* __restrict__ bi, const float* __restrict__ bl,
    const float* __restrict__ Wo, const float* __restrict__ bo,
    float* __restrict__ t, int K, int Nn)
{
    __shared__ float xs[16][65];
    __shared__ float ws[16][65];
    const int tid = threadIdx.x;
    const int tx = tid & 15, ty = tid >> 4;
    const int row0 = blockIdx.x * 64;
    const int n = blockIdx.y;
    const float* Wn = Wi + (size_t)n * K * 64;
    float acc[4][4] = {};
    for (int k0 = 0; k0 < K; k0 += 16) {
#pragma unroll
        for (int i = 0; i < 4; ++i) {
            int li = tid + 256 * i;
            xs[li & 15][li >> 4] = x[(size_t)(row0 + (li >> 4)) * K + k0 + (li & 15)];
        }
#pragma unroll
        for (int i = 0; i < 4; ++i) {
            int li = tid + 256 * i;
            ws[li >> 6][li & 63] = Wn[(size_t)(k0 + (li >> 6)) * 64 + (li & 63)];
        }
        __syncthreads();
#pragma unroll
        for (int kk = 0; kk < 16; ++kk) {
            float xa[4], wb[4];
#pragma unroll
            for (int i = 0; i < 4; ++i) xa[i] = xs[kk][4 * ty + i];
#pragma unroll
            for (int j = 0; j < 4; ++j) wb[j] = ws[kk][4 * tx + j];
#pragma unroll
            for (int i = 0; i < 4; ++i)
#pragma unroll
                for (int j = 0; j < 4; ++j) acc[i][j] += xa[i] * wb[j];
        }
        __syncthreads();
    }
    float part[4] = {0.f, 0.f, 0.f, 0.f};
#pragma unroll
    for (int j = 0; j < 4; ++j) {
        int cc = 4 * tx + j;
        float bias = bi[n * 64 + cc] + bl[n * 64 + cc];
        float wov = Wo[n * 64 + cc];
#pragma unroll
        for (int i = 0; i < 4; ++i) {
            float v = acc[i][j] + bias;
            part[i] += (tanhf(v) + 0.1f * sinf(0.5f * v) * cosf(0.3f * v)) * wov;
        }
    }
#pragma unroll
    for (int mk = 1; mk < 16; mk <<= 1)
#pragma unroll
        for (int i = 0; i < 4; ++i) part[i] += __shfl_xor(part[i], mk, 64);
    if (tx == 0) {
        float b = bo[n];
#pragma unroll
        for (int i = 0; i < 4; ++i)
            t[(size_t)(row0 + 4 * ty + i) * Nn + n] = part[i] + b;
    }
}

__global__ void lateral_f32_kernel(const float* __restrict__ t,
                                   const float* __restrict__ L,
                                   const float* __restrict__ a,
                                   float* __restrict__ h, int Nn)
{
    extern __shared__ float tb[];
    const int b = blockIdx.x;
    const int n = threadIdx.x;
    tb[n] = t[(size_t)b * Nn + n];
    __syncthreads();
    float acc = 0.f;
    for (int mm = 0; mm < Nn; ++mm)
        acc += tb[mm] * L[(size_t)mm * Nn + n];
    h[(size_t)b * Nn + n] = (tb[n] + 0.1f * acc) * a[n];
}

__global__ void out_f32_kernel(const float* __restrict__ h,
                               const float* __restrict__ Wout,
                               const float* __restrict__ bout,
                               float* __restrict__ y)
{
    int g = blockIdx.x * blockDim.x + threadIdx.x;
    if (g >= BATCH * 12) return;
    int b = g / 12, o = g - 12 * b;
    float acc = bout[o];
    const float* hb = h + (size_t)b * 64;
#pragma unroll
    for (int k = 0; k < 64; ++k) acc += hb[k] * Wout[k * 12 + o];
    y[g] = acc;
}

extern "C" void kernel_launch(void* const* d_in, const int* in_sizes, int n_in,
                              void* d_out, int out_size, void* d_ws, size_t ws_size,
                              hipStream_t stream)
{
    (void)in_sizes; (void)n_in; (void)out_size;
    const float* x = (const float*)d_in[0];
    const float* Wout = (const float*)d_in[22];
    const float* bout = (const float*)d_in[23];
    const int dims[4] = {512, 256, 128, 64};
    char* ws = (char*)d_ws;
    const size_t MB = 1024u * 1024u;

    if (ws_size >= 27 * MB) {
        // Wt0 [0,16) Wt1 [16,20) Wt2 [20,21) xb [21,25) (h0 [21,23), h1 [23,24))
        // tbuf [25,27)
        __hip_bfloat16* Wt0 = (__hip_bfloat16*)ws;
        __hip_bfloat16* Wt1 = (__hip_bfloat16*)(ws + 16 * MB);
        __hip_bfloat16* Wt2 = (__hip_bfloat16*)(ws + 20 * MB);
        __hip_bfloat16* Wts[3] = {Wt0, Wt1, Wt2};
        __hip_bfloat16* xb = (__hip_bfloat16*)(ws + 21 * MB);
        __hip_bfloat16* h0 = xb;
        __hip_bfloat16* h1 = (__hip_bfloat16*)(ws + 23 * MB);
        __hip_bfloat16* tbuf = (__hip_bfloat16*)(ws + 25 * MB);

        conv_all<<<4736, 256, 0, stream>>>(
            x, xb, (const float*)d_in[1], (const float*)d_in[8],
            (const float*)d_in[15], Wt0, Wt1, Wt2);

        const __hip_bfloat16* prev = xb;
        const __hip_bfloat16* hbuf[3] = {h0, h1, nullptr};
        for (int l = 0; l < 3; ++l) {
            const float* bi = (const float*)d_in[1 + 7 * l + 1];
            const float* bl = (const float*)d_in[1 + 7 * l + 2];
            const float* Wo = (const float*)d_in[1 + 7 * l + 3];
            const float* bo = (const float*)d_in[1 + 7 * l + 4];
            const float* L  = (const float*)d_in[1 + 7 * l + 5];
            const float* a  = (const float*)d_in[1 + 7 * l + 6];
            const int K = dims[l], Nn = dims[l + 1];

            liquid_proj_mfma<<<64 * (Nn / 4), 512, 0, stream>>>(
                prev, Wts[l], bi, bl, Wo, bo, tbuf, K, Nn);
            if (l == 0)
                lateral_fused<256, 8, false><<<BATCH / 16, 256, 0, stream>>>(
                    tbuf, L, a, h0, nullptr, nullptr, nullptr);
            else if (l == 1)
                lateral_fused<128, 7, false><<<BATCH / 16, 256, 0, stream>>>(
                    tbuf, L, a, h1, nullptr, nullptr, nullptr);
            else
                lateral_fused<64, 6, true><<<BATCH / 16, 256, 0, stream>>>(
                    tbuf, L, a, nullptr, Wout, bout, (float*)d_out);
            prev = hbuf[l];
        }
    } else {
        float* tbufs[3] = {(float*)ws, (float*)ws, (float*)(ws + 4 * MB)};
        float* hs[3] = {(float*)(ws + 4 * MB), (float*)(ws + 2 * MB),
                        (float*)(ws + 5 * MB)};
        const float* prev = x;
        for (int l = 0; l < 3; ++l) {
            const float* Wi = (const float*)d_in[1 + 7 * l + 0];
            const float* bi = (const float*)d_in[1 + 7 * l + 1];
            const float* bl = (const float*)d_in[1 + 7 * l + 2];
            const float* Wo = (const float*)d_in[1 + 7 * l + 3];
            const float* bo = (const float*)d_in[1 + 7 * l + 4];
            const float* L  = (const float*)d_in[1 + 7 * l + 5];
            const float* a  = (const float*)d_in[1 + 7 * l + 6];
            const int K = dims[l], Nn = dims[l + 1];
            liquid_proj_f32<<<dim3(BATCH / 64, Nn), 256, 0, stream>>>(
                prev, Wi, bi, bl, Wo, bo, tbufs[l], K, Nn);
            lateral_f32_kernel<<<BATCH, Nn, Nn * sizeof(float), stream>>>(
                tbufs[l], L, a, hs[l], Nn);
            prev = hs[l];
        }
        out_f32_kernel<<<(BATCH * 12 + 255) / 256, 256, 0, stream>>>(
            hs[2], Wout, bout, (float*)d_out);
    }
}